// Round 9
// baseline (125.343 us; speedup 1.0000x reference)
//
#include <hip/hip_runtime.h>

#define B_  4
#define V_  5
#define J_  15
#define H_  128
#define W_  240
#define HW_ (H_ * W_)          // 30720
#define N_  128000             // 80*80*20
#define NB_ (N_ / 256)         // blocks per batch for fallback kernel

// ---------------------------------------------------------------------------
// Quantize+transpose heatmaps (B*V, J, H*W) fp32 -> (B*V, H*W, 16) u8.
// value stored = round(v*255); dequant 1/255 folded into sample kernel.
// BW-bound (~47 MB moved, ~8 us).
// ---------------------------------------------------------------------------
__global__ __launch_bounds__(256) void quant_u8_k(const float* __restrict__ src,
                                                  uint4* __restrict__ dst) {
    const int bv = blockIdx.y;
    const int p  = blockIdx.x * 256 + threadIdx.x;
    const float* sb = src + (size_t)bv * J_ * HW_;

    unsigned r[4] = {0u, 0u, 0u, 0u};
    #pragma unroll
    for (int j = 0; j < J_; ++j) {
        float f = sb[(size_t)j * HW_ + p];
        f = fminf(fmaxf(f, 0.0f), 1.0f);
        const unsigned u = (unsigned)__float2int_rn(f * 255.0f);
        r[j >> 2] |= u << ((j & 3) * 8);
    }
    dst[(size_t)bv * HW_ + p] = make_uint4(r[0], r[1], r[2], r[3]);   // j=15 byte = 0
}

// acc[0..15] += u0 * byte_j(a) + u1 * byte_j(b)   (16 u8 joints per pixel line)
__device__ inline void accum16_2(const uint4 a, const uint4 b,
                                 const float u0, const float u1, float* acc) {
    const unsigned sa[4] = {a.x, a.y, a.z, a.w};
    const unsigned sb[4] = {b.x, b.y, b.z, b.w};
    #pragma unroll
    for (int i = 0; i < 4; ++i) {
        #pragma unroll
        for (int k = 0; k < 4; ++k) {
            const float fa = (float)((sa[i] >> (8 * k)) & 0xFFu);
            const float fb = (float)((sb[i] >> (8 * k)) & 0xFFu);
            acc[4 * i + k] = fmaf(u0, fa, fmaf(u1, fb, acc[4 * i + k]));
        }
    }
}

// ---------------------------------------------------------------------------
// Bilinear sample from u8 pixel-major layout, TWO lanes per (b,n) sample,
// x-pair corner merge: lane q owns column x_q and loads the FULL 16B pixel
// line at rows y0 and y1 (10 loads/sample vs 20; pair addresses are
// contiguous 32B -> fewer TA transactions). Per-lane fold: u0 = wx_q*wy0,
// u1 = wx_q*wy1.
// Round-8 bug fix: the final column sum must shuffle the SAME acc register
// index on both lanes. Loop j uniformly over 0..14, shfl_xor(acc[j],1), and
// predicate only the store by ownership ((j>>3)==q). Round 8 indexed acc[]
// lane-dependently inside the shuffle -> exchanged joint j with joint j+8.
// b = blockIdx & 3: batch b's 2.45 MB u8 slice stays L2-resident.
// ---------------------------------------------------------------------------
__global__ __launch_bounds__(256) void sample_u8_k(const uint4* __restrict__ hmq,
                                                   const float2* __restrict__ grid,
                                                   float* __restrict__ out) {
    const int b     = blockIdx.x & 3;
    const int chunk = blockIdx.x >> 2;          // 0..999
    const int q     = threadIdx.x & 1;
    const int n     = chunk * 128 + (threadIdx.x >> 1);

    float u0[V_], u1[V_];
    int   offA[V_], offB[V_];

    #pragma unroll
    for (int v = 0; v < V_; ++v) {
        const int bv = b * V_ + v;
        const float2 g = grid[(size_t)bv * N_ + n];   // lane pair: broadcast

        const float ix = (g.x + 1.0f) * 0.5f * (float)(W_ - 1);
        const float iy = (g.y + 1.0f) * 0.5f * (float)(H_ - 1);
        const float x0f = floorf(ix), y0f = floorf(iy);
        const float wx1 = ix - x0f,   wy1 = iy - y0f;
        const float wx0 = 1.0f - wx1, wy0 = 1.0f - wy1;
        const int x0 = (int)x0f, y0 = (int)y0f;
        const int x1 = x0 + 1,   y1 = y0 + 1;

        const float vx0 = (x0 >= 0 && x0 <= W_ - 1) ? wx0 : 0.0f;
        const float vx1 = (x1 >= 0 && x1 <= W_ - 1) ? wx1 : 0.0f;
        const float vy0 = (y0 >= 0 && y0 <= H_ - 1) ? wy0 : 0.0f;
        const float vy1 = (y1 >= 0 && y1 <= H_ - 1) ? wy1 : 0.0f;

        const int cx0 = min(max(x0, 0), W_ - 1), cx1 = min(max(x1, 0), W_ - 1);
        const int cy0 = min(max(y0, 0), H_ - 1), cy1 = min(max(y1, 0), H_ - 1);

        const int   cxq = q ? cx1 : cx0;            // this lane's column
        const float vxq = q ? vx1 : vx0;
        u0[v] = vxq * vy0;                          // weight for row y0
        u1[v] = vxq * vy1;                          // weight for row y1

        const int base = bv * HW_;
        offA[v] = base + cy0 * W_ + cxq;
        offB[v] = base + cy1 * W_ + cxq;
    }

    __builtin_amdgcn_sched_barrier(0);   // addresses done; now ONLY loads

    uint4 cA[V_], cB[V_];
    #pragma unroll
    for (int v = 0; v < V_; ++v) {
        cA[v] = hmq[offA[v]];
        cB[v] = hmq[offB[v]];
    }

    __builtin_amdgcn_sched_barrier(0);   // all 10 loads in flight before accum

    float acc[16];
    #pragma unroll
    for (int j = 0; j < 16; ++j) acc[j] = 0.0f;

    #pragma unroll
    for (int v = 0; v < V_; ++v)
        accum16_2(cA[v], cB[v], u0[v], u1[v], acc);

    const float s = 1.0f / (255.0f * (float)V_);   // dequant * mean fold
    const size_t ob = (size_t)b * J_ * N_ + n;
    #pragma unroll
    for (int j = 0; j < J_; ++j) {
        // uniform j on both lanes -> shuffle pairs matching registers
        const float tot = acc[j] + __shfl_xor(acc[j], 1, 64);
        if ((j >> 3) == q) {                       // lane 0 owns j 0..7, lane 1 owns 8..14
            const float r = fminf(fmaxf(tot * s, 0.0f), 1.0f);
            out[ob + (size_t)j * N_] = r;
        }
    }
}

// ---------------------------------------------------------------------------
// Fallback: direct gather from original (J,H,W) layout (if ws too small).
// ---------------------------------------------------------------------------
__global__ __launch_bounds__(256) void sample_direct_k(const float* __restrict__ hm,
                                                       const float* __restrict__ grid,
                                                       float* __restrict__ out) {
    const int b = blockIdx.x / NB_;
    const int n = (blockIdx.x % NB_) * 256 + threadIdx.x;

    float acc[J_];
    #pragma unroll
    for (int j = 0; j < J_; ++j) acc[j] = 0.0f;

    #pragma unroll
    for (int v = 0; v < V_; ++v) {
        const int bv = b * V_ + v;
        const float2 g = ((const float2*)grid)[(size_t)bv * N_ + n];

        const float ix = (g.x + 1.0f) * 0.5f * (float)(W_ - 1);
        const float iy = (g.y + 1.0f) * 0.5f * (float)(H_ - 1);
        const float x0f = floorf(ix), y0f = floorf(iy);
        const float wx1 = ix - x0f,   wy1 = iy - y0f;
        const float wx0 = 1.0f - wx1, wy0 = 1.0f - wy1;
        const int x0 = (int)x0f, y0 = (int)y0f;
        const int x1 = x0 + 1,   y1 = y0 + 1;

        const float vx0 = (x0 >= 0 && x0 <= W_ - 1) ? wx0 : 0.0f;
        const float vx1 = (x1 >= 0 && x1 <= W_ - 1) ? wx1 : 0.0f;
        const float vy0 = (y0 >= 0 && y0 <= H_ - 1) ? wy0 : 0.0f;
        const float vy1 = (y1 >= 0 && y1 <= H_ - 1) ? wy1 : 0.0f;

        const int cx0 = min(max(x0, 0), W_ - 1), cx1 = min(max(x1, 0), W_ - 1);
        const int cy0 = min(max(y0, 0), H_ - 1), cy1 = min(max(y1, 0), H_ - 1);

        const float w00 = vx0 * vy0, w01 = vx1 * vy0;
        const float w10 = vx0 * vy1, w11 = vx1 * vy1;

        const int o00 = cy0 * W_ + cx0, o01 = cy0 * W_ + cx1;
        const int o10 = cy1 * W_ + cx0, o11 = cy1 * W_ + cx1;

        const float* base = hm + (size_t)bv * J_ * HW_;
        #pragma unroll
        for (int j = 0; j < J_; ++j) {
            const float* p = base + (size_t)j * HW_;
            acc[j] = fmaf(w00, p[o00],
                     fmaf(w01, p[o01],
                     fmaf(w10, p[o10],
                     fmaf(w11, p[o11], acc[j]))));
        }
    }

    const size_t ob = (size_t)b * J_ * N_ + n;
    #pragma unroll
    for (int j = 0; j < J_; ++j) {
        float r = acc[j] * (1.0f / V_);
        r = fminf(fmaxf(r, 0.0f), 1.0f);
        out[ob + (size_t)j * N_] = r;
    }
}

extern "C" void kernel_launch(void* const* d_in, const int* in_sizes, int n_in,
                              void* d_out, int out_size, void* d_ws, size_t ws_size,
                              hipStream_t stream) {
    const float* hm   = (const float*)d_in[0];   // (B,V,J,H,W) fp32
    const float* grid = (const float*)d_in[1];   // (B,V,1,N,2) fp32
    float* out = (float*)d_out;                  // (B,J,80,80,20) fp32

    const size_t need = (size_t)B_ * V_ * HW_ * 16;  // 9.83 MB u8
    if (ws_size >= need) {
        uint4* hmq = (uint4*)d_ws;
        // 256 pixels per block -> HW_/256 = 120 blocks in x
        quant_u8_k<<<dim3(HW_ / 256, B_ * V_), 256, 0, stream>>>(hm, hmq);
        // 2 lanes per sample: B*N*2 = 1,024,000 threads -> 4000 blocks
        sample_u8_k<<<B_ * (N_ / 128), 256, 0, stream>>>(hmq,
                                                         (const float2*)grid, out);
    } else {
        sample_direct_k<<<B_ * NB_, 256, 0, stream>>>(hm, grid, out);
    }
}

// Round 10
// 123.910 us; speedup vs baseline: 1.0116x; 1.0116x over previous
//
#include <hip/hip_runtime.h>

#define B_  4
#define V_  5
#define J_  15
#define H_  128
#define W_  240
#define HW_ (H_ * W_)          // 30720
#define N_  128000             // 80*80*20
#define NB_ (N_ / 256)         // blocks per batch for fallback kernel

// ---------------------------------------------------------------------------
// Quantize+transpose heatmaps (B*V, J, H*W) fp32 -> (B*V, H*W, 16) u8.
// value stored = round(v*255); dequant 1/255 folded into sample kernel.
// BW-bound (~47 MB moved, ~8 us).
// ---------------------------------------------------------------------------
__global__ __launch_bounds__(256) void quant_u8_k(const float* __restrict__ src,
                                                  uint4* __restrict__ dst) {
    const int bv = blockIdx.y;
    const int p  = blockIdx.x * 256 + threadIdx.x;
    const float* sb = src + (size_t)bv * J_ * HW_;

    unsigned r[4] = {0u, 0u, 0u, 0u};
    #pragma unroll
    for (int j = 0; j < J_; ++j) {
        float f = sb[(size_t)j * HW_ + p];
        f = fminf(fmaxf(f, 0.0f), 1.0f);
        const unsigned u = (unsigned)__float2int_rn(f * 255.0f);
        r[j >> 2] |= u << ((j & 3) * 8);
    }
    dst[(size_t)bv * HW_ + p] = make_uint4(r[0], r[1], r[2], r[3]);   // j=15 byte = 0
}

// acc[0..7] += w * byte_k(u)   (8 bytes of one uint2)
__device__ inline void accum8u(const uint2 u, const float w, float* acc) {
    const unsigned s[2] = {u.x, u.y};
    #pragma unroll
    for (int i = 0; i < 2; ++i) {
        acc[4 * i + 0] = fmaf(w, (float)(s[i] & 0xFFu),         acc[4 * i + 0]);
        acc[4 * i + 1] = fmaf(w, (float)((s[i] >> 8) & 0xFFu),  acc[4 * i + 1]);
        acc[4 * i + 2] = fmaf(w, (float)((s[i] >> 16) & 0xFFu), acc[4 * i + 2]);
        acc[4 * i + 3] = fmaf(w, (float)(s[i] >> 24),           acc[4 * i + 3]);
    }
}

// ---------------------------------------------------------------------------
// Bilinear sample from u8 pixel-major layout, TWO lanes per (b,n) sample
// (Round-7 measured-best configuration, restored after R8/R9 regressions).
// Lane q loads the q-th 8B half of each 16B corner line (pair merges to one
// TA transaction) and owns joints 8q..8q+7 — no cross-lane reduction needed.
// sched_barrier fences keep all 20 gathers in one in-flight window.
// b = blockIdx & 3: batch b's 2.45 MB u8 slice stays L2-resident
// (R5 counters: FETCH ~= grid-only; heatmap HBM traffic ~0).
// ---------------------------------------------------------------------------
__global__ __launch_bounds__(256) void sample_u8_k(const uint2* __restrict__ hmq,
                                                   const float2* __restrict__ grid,
                                                   float* __restrict__ out) {
    const int b     = blockIdx.x & 3;
    const int chunk = blockIdx.x >> 2;          // 0..999
    const int q     = threadIdx.x & 1;
    const int n     = chunk * 128 + (threadIdx.x >> 1);

    float w[V_][4];
    int   off[V_][4];

    #pragma unroll
    for (int v = 0; v < V_; ++v) {
        const int bv = b * V_ + v;
        const float2 g = grid[(size_t)bv * N_ + n];   // lane pair: broadcast

        const float ix = (g.x + 1.0f) * 0.5f * (float)(W_ - 1);
        const float iy = (g.y + 1.0f) * 0.5f * (float)(H_ - 1);
        const float x0f = floorf(ix), y0f = floorf(iy);
        const float wx1 = ix - x0f,   wy1 = iy - y0f;
        const float wx0 = 1.0f - wx1, wy0 = 1.0f - wy1;
        const int x0 = (int)x0f, y0 = (int)y0f;
        const int x1 = x0 + 1,   y1 = y0 + 1;

        const float vx0 = (x0 >= 0 && x0 <= W_ - 1) ? wx0 : 0.0f;
        const float vx1 = (x1 >= 0 && x1 <= W_ - 1) ? wx1 : 0.0f;
        const float vy0 = (y0 >= 0 && y0 <= H_ - 1) ? wy0 : 0.0f;
        const float vy1 = (y1 >= 0 && y1 <= H_ - 1) ? wy1 : 0.0f;

        const int cx0 = min(max(x0, 0), W_ - 1), cx1 = min(max(x1, 0), W_ - 1);
        const int cy0 = min(max(y0, 0), H_ - 1), cy1 = min(max(y1, 0), H_ - 1);

        w[v][0] = vx0 * vy0;  w[v][1] = vx1 * vy0;
        w[v][2] = vx0 * vy1;  w[v][3] = vx1 * vy1;

        // uint2 index = pixel*2 + q
        const int base = (bv * HW_) * 2 + q;
        off[v][0] = base + (cy0 * W_ + cx0) * 2;
        off[v][1] = base + (cy0 * W_ + cx1) * 2;
        off[v][2] = base + (cy1 * W_ + cx0) * 2;
        off[v][3] = base + (cy1 * W_ + cx1) * 2;
    }

    __builtin_amdgcn_sched_barrier(0);   // addresses done; now ONLY loads

    uint2 c[V_][4];
    #pragma unroll
    for (int v = 0; v < V_; ++v)
        #pragma unroll
        for (int k = 0; k < 4; ++k)
            c[v][k] = hmq[off[v][k]];

    __builtin_amdgcn_sched_barrier(0);   // all 20 loads issued before any accum

    float acc[8];
    #pragma unroll
    for (int j = 0; j < 8; ++j) acc[j] = 0.0f;

    #pragma unroll
    for (int v = 0; v < V_; ++v)
        #pragma unroll
        for (int k = 0; k < 4; ++k)
            accum8u(c[v][k], w[v][k], acc);

    const float s = 1.0f / (255.0f * (float)V_);   // dequant * mean fold
    const size_t ob = (size_t)b * J_ * N_ + n;
    const int j0 = q * 8;
    #pragma unroll
    for (int k = 0; k < 8; ++k) {
        if (j0 + k < J_) {
            const float r = fminf(fmaxf(acc[k] * s, 0.0f), 1.0f);
            out[ob + (size_t)(j0 + k) * N_] = r;
        }
    }
}

// ---------------------------------------------------------------------------
// Fallback: direct gather from original (J,H,W) layout (if ws too small).
// ---------------------------------------------------------------------------
__global__ __launch_bounds__(256) void sample_direct_k(const float* __restrict__ hm,
                                                       const float* __restrict__ grid,
                                                       float* __restrict__ out) {
    const int b = blockIdx.x / NB_;
    const int n = (blockIdx.x % NB_) * 256 + threadIdx.x;

    float acc[J_];
    #pragma unroll
    for (int j = 0; j < J_; ++j) acc[j] = 0.0f;

    #pragma unroll
    for (int v = 0; v < V_; ++v) {
        const int bv = b * V_ + v;
        const float2 g = ((const float2*)grid)[(size_t)bv * N_ + n];

        const float ix = (g.x + 1.0f) * 0.5f * (float)(W_ - 1);
        const float iy = (g.y + 1.0f) * 0.5f * (float)(H_ - 1);
        const float x0f = floorf(ix), y0f = floorf(iy);
        const float wx1 = ix - x0f,   wy1 = iy - y0f;
        const float wx0 = 1.0f - wx1, wy0 = 1.0f - wy1;
        const int x0 = (int)x0f, y0 = (int)y0f;
        const int x1 = x0 + 1,   y1 = y0 + 1;

        const float vx0 = (x0 >= 0 && x0 <= W_ - 1) ? wx0 : 0.0f;
        const float vx1 = (x1 >= 0 && x1 <= W_ - 1) ? wx1 : 0.0f;
        const float vy0 = (y0 >= 0 && y0 <= H_ - 1) ? wy0 : 0.0f;
        const float vy1 = (y1 >= 0 && y1 <= H_ - 1) ? wy1 : 0.0f;

        const int cx0 = min(max(x0, 0), W_ - 1), cx1 = min(max(x1, 0), W_ - 1);
        const int cy0 = min(max(y0, 0), H_ - 1), cy1 = min(max(y1, 0), H_ - 1);

        const float w00 = vx0 * vy0, w01 = vx1 * vy0;
        const float w10 = vx0 * vy1, w11 = vx1 * vy1;

        const int o00 = cy0 * W_ + cx0, o01 = cy0 * W_ + cx1;
        const int o10 = cy1 * W_ + cx0, o11 = cy1 * W_ + cx1;

        const float* base = hm + (size_t)bv * J_ * HW_;
        #pragma unroll
        for (int j = 0; j < J_; ++j) {
            const float* p = base + (size_t)j * HW_;
            acc[j] = fmaf(w00, p[o00],
                     fmaf(w01, p[o01],
                     fmaf(w10, p[o10],
                     fmaf(w11, p[o11], acc[j]))));
        }
    }

    const size_t ob = (size_t)b * J_ * N_ + n;
    #pragma unroll
    for (int j = 0; j < J_; ++j) {
        float r = acc[j] * (1.0f / V_);
        r = fminf(fmaxf(r, 0.0f), 1.0f);
        out[ob + (size_t)j * N_] = r;
    }
}

extern "C" void kernel_launch(void* const* d_in, const int* in_sizes, int n_in,
                              void* d_out, int out_size, void* d_ws, size_t ws_size,
                              hipStream_t stream) {
    const float* hm   = (const float*)d_in[0];   // (B,V,J,H,W) fp32
    const float* grid = (const float*)d_in[1];   // (B,V,1,N,2) fp32
    float* out = (float*)d_out;                  // (B,J,80,80,20) fp32

    const size_t need = (size_t)B_ * V_ * HW_ * 16;  // 9.83 MB u8
    if (ws_size >= need) {
        uint4* hmq = (uint4*)d_ws;
        // 256 pixels per block -> HW_/256 = 120 blocks in x
        quant_u8_k<<<dim3(HW_ / 256, B_ * V_), 256, 0, stream>>>(hm, hmq);
        // 2 lanes per sample: B*N*2 = 1,024,000 threads -> 4000 blocks
        sample_u8_k<<<B_ * (N_ / 128), 256, 0, stream>>>((const uint2*)hmq,
                                                         (const float2*)grid, out);
    } else {
        sample_direct_k<<<B_ * NB_, 256, 0, stream>>>(hm, grid, out);
    }
}